// Round 14
// baseline (310.409 us; speedup 1.0000x reference)
//
#include <hip/hip_runtime.h>
#include <hip/hip_bf16.h>
#include <math.h>

typedef __hip_bfloat16 bf16;
typedef __attribute__((ext_vector_type(8))) short short8;
typedef __attribute__((ext_vector_type(4))) float f32x4;

#define BB 4
#define LL 1024
#define DD 768
#define HH 12
#define DK 64
#define FF_ 3072
#define PP 32
#define MAXD 256

// async global->LDS, 16B per lane. LDS dest: wave-uniform base + lane*16.
__device__ __forceinline__ void async_load16(const void* g, void* l) {
    __builtin_amdgcn_global_load_lds(
        (const __attribute__((address_space(1))) unsigned int*)g,
        (__attribute__((address_space(3))) unsigned int*)l, 16, 0, 0);
}

// ---------------- LayerNorm (fp32 in, bf16 out) ----------------
__global__ __launch_bounds__(256) void ln_kernel(const float* __restrict__ x,
                                                 const float* __restrict__ g,
                                                 const float* __restrict__ b,
                                                 float eps,
                                                 bf16* __restrict__ y) {
    const int row = blockIdx.x;
    const int tid = threadIdx.x;
    const float* xr = x + (size_t)row * DD;

    float v[3];
    float s = 0.f, ss = 0.f;
#pragma unroll
    for (int i = 0; i < 3; ++i) {
        float t = xr[tid + i * 256];
        v[i] = t; s += t; ss += t * t;
    }
    __shared__ float rs[256], rss[256];
    rs[tid] = s; rss[tid] = ss;
    __syncthreads();
    for (int off = 128; off; off >>= 1) {
        if (tid < off) { rs[tid] += rs[tid + off]; rss[tid] += rss[tid + off]; }
        __syncthreads();
    }
    const float mean = rs[0] * (1.f / DD);
    const float var  = rss[0] * (1.f / DD) - mean * mean;
    const float inv  = rsqrtf(var + eps);
#pragma unroll
    for (int i = 0; i < 3; ++i) {
        int c = tid + i * 256;
        y[(size_t)row * DD + c] = __float2bfloat16((v[i] - mean) * inv * g[c] + b[c]);
    }
}

// ---------------- fused: LN1 + all weight transposes + bias pack ----------------
__global__ __launch_bounds__(256) void prep_ln(
        const float* __restrict__ x,
        const float* __restrict__ ln1_g, const float* __restrict__ ln1_b,
        const float* __restrict__ Wq, const float* __restrict__ Wk,
        const float* __restrict__ Wv, const float* __restrict__ Wo,
        const float* __restrict__ W1, const float* __restrict__ W2,
        const float* __restrict__ bq, const float* __restrict__ bk,
        const float* __restrict__ bv,
        bf16* __restrict__ y_ln,
        bf16* __restrict__ WtQKV, bf16* __restrict__ WtO,
        bf16* __restrict__ Wt1, bf16* __restrict__ Wt2,
        float* __restrict__ bqkv) {
    const int bid = blockIdx.x;
    const int tid = threadIdx.x;

    if (bid < 4096) {                       // ---- LN1 ----
        const float* xr = x + (size_t)bid * DD;
        float v[3];
        float s = 0.f, ss = 0.f;
#pragma unroll
        for (int i = 0; i < 3; ++i) {
            float t = xr[tid + i * 256];
            v[i] = t; s += t; ss += t * t;
        }
        __shared__ float rs[256], rss[256];
        rs[tid] = s; rss[tid] = ss;
        __syncthreads();
        for (int off = 128; off; off >>= 1) {
            if (tid < off) { rs[tid] += rs[tid + off]; rss[tid] += rss[tid + off]; }
            __syncthreads();
        }
        const float mean = rs[0] * (1.f / DD);
        const float var  = rss[0] * (1.f / DD) - mean * mean;
        const float inv  = rsqrtf(var + 1e-6f);
#pragma unroll
        for (int i = 0; i < 3; ++i) {
            int c = tid + i * 256;
            y_ln[(size_t)bid * DD + c] = __float2bfloat16((v[i] - mean) * inv * ln1_g[c] + ln1_b[c]);
        }
        return;
    }
    if (bid >= 11008) {                     // ---- bias pack ----
        int i = (bid - 11008) * 256 + tid;
        if (i < 2304) {
            float v = (i < 768) ? bq[i] : (i < 1536) ? bk[i - 768] : bv[i - 1536];
            bqkv[i] = v;
        }
        return;
    }
    // ---- transposes ----
    const int tb = bid - 4096;
    const float* W; bf16* Wt; int K, N, tile;
    if (tb < 576)       { W = Wq; Wt = WtQKV;                      K = DD;  N = DD;  tile = tb; }
    else if (tb < 1152) { W = Wk; Wt = WtQKV + (size_t)768 * DD;   K = DD;  N = DD;  tile = tb - 576; }
    else if (tb < 1728) { W = Wv; Wt = WtQKV + (size_t)1536 * DD;  K = DD;  N = DD;  tile = tb - 1152; }
    else if (tb < 2304) { W = Wo; Wt = WtO;                        K = DD;  N = DD;  tile = tb - 1728; }
    else if (tb < 4608) { W = W1; Wt = Wt1;                        K = DD;  N = FF_; tile = tb - 2304; }
    else                { W = W2; Wt = Wt2;                        K = FF_; N = DD;  tile = tb - 4608; }
    const int ntn = N / 32;
    const int n0 = (tile % ntn) * 32, k0 = (tile / ntn) * 32;

    __shared__ float tilebuf[32][33];
    const int tx = tid & 31, ty = tid >> 5;
#pragma unroll
    for (int i = 0; i < 4; ++i) {
        int k = ty + i * 8;
        tilebuf[k][tx] = W[(size_t)(k0 + k) * N + n0 + tx];
    }
    __syncthreads();
#pragma unroll
    for (int i = 0; i < 4; ++i) {
        int n = ty + i * 8;
        Wt[(size_t)(n0 + n) * K + k0 + tx] = __float2bfloat16(tilebuf[tx][n]);
    }
}

// ---------------- FF2 split-K(4, bf16 partials) reduce + bias + out1 residual ----------------
__global__ __launch_bounds__(256) void ff2_reduce(const bf16* __restrict__ Fp,
                                                  const float* __restrict__ out1,
                                                  const float* __restrict__ b2,
                                                  float* __restrict__ dout) {
    const size_t stride = (size_t)BB * LL * DD;
    const size_t i8 = ((size_t)blockIdx.x * 256 + threadIdx.x) * 8;
    const int c = (int)(i8 % DD);

    float acc[8];
    float4 r0 = *(const float4*)(out1 + i8);
    float4 r1 = *(const float4*)(out1 + i8 + 4);
    float4 bb0 = *(const float4*)(b2 + c);
    float4 bb1 = *(const float4*)(b2 + c + 4);
    acc[0] = r0.x + bb0.x; acc[1] = r0.y + bb0.y; acc[2] = r0.z + bb0.z; acc[3] = r0.w + bb0.w;
    acc[4] = r1.x + bb1.x; acc[5] = r1.y + bb1.y; acc[6] = r1.z + bb1.z; acc[7] = r1.w + bb1.w;
#pragma unroll
    for (int p = 0; p < 4; ++p) {
        short8 v = *(const short8*)(Fp + p * stride + i8);
#pragma unroll
        for (int k = 0; k < 8; ++k) acc[k] += __bfloat162float(((const bf16*)&v)[k]);
    }
    float4 o0 = {acc[0], acc[1], acc[2], acc[3]};
    float4 o1 = {acc[4], acc[5], acc[6], acc[7]};
    *(float4*)(dout + i8) = o0;
    *(float4*)(dout + i8 + 4) = o1;
}

// ---------------- MFMA GEMM: templated TMxTN tile, dbuf LDS, XCD-swizzled, split-K ----------------
// C = act(A @ Bt^T + bias) (+res). BK=32. waves 2x2; wave frag block (TM/2)x(TN/2).
// Grid must satisfy gridDim.y*gridDim.z % 8 == 0 for the XCD swizzle.
template <int TM, int TN, int RES, bool GELU, bool SPLIT_QKV, int KSPLIT, typename OutT>
__global__ __launch_bounds__(256) void mfma_gemm_bt(const bf16* __restrict__ A,
                                                    const bf16* __restrict__ Bt,
                                                    const float* __restrict__ bias,
                                                    const float* __restrict__ res,
                                                    OutT* __restrict__ C,
                                                    bf16* __restrict__ QhOut,
                                                    bf16* __restrict__ KhOut,
                                                    bf16* __restrict__ VtOut,
                                                    int M, int N, int K) {
    constexpr int WM = TM / 32;      // m-frags per wave
    constexpr int WN = TN / 32;      // n-frags per wave
    constexpr int CA = TM / 64;      // A staging instrs per wave
    constexpr int CB = TN / 64;
    __shared__ short As[2][TM * 32];
    __shared__ short Bs[2][TN * 32];

    const int L = blockIdx.x + gridDim.x * (blockIdx.y + gridDim.y * blockIdx.z);
    const int xcd = L & 7, j = L >> 3;
    const int col = j % gridDim.x;
    const int panel = xcd + 8 * (j / gridDim.x);
    const int byy = panel % gridDim.y;
    const int bzz = panel / gridDim.y;

    const int bm = byy * TM, bn = col * TN;
    const int tid = threadIdx.x;
    const int w = tid >> 6, lane = tid & 63;
    const int c16 = lane & 15, quad = lane >> 4;
    const int wy = w >> 1, wx = w & 1;

    const int srow_in = lane >> 2;
    const int cg = (lane & 3) ^ quad;

    const int Ksub = K / KSPLIT;
    const int kbase = bzz * Ksub;

    f32x4 acc[WM][WN];
#pragma unroll
    for (int i = 0; i < WM; ++i)
#pragma unroll
        for (int j2 = 0; j2 < WN; ++j2) acc[i][j2] = (f32x4)0.f;

    auto stage = [&](int buf, int k0) {
#pragma unroll
        for (int j2 = 0; j2 < CA; ++j2) {
            const int ci = w * CA + j2;
            const int row = ci * 16 + srow_in;
            async_load16(A + (size_t)(bm + row) * K + k0 + cg * 8, (char*)As[buf] + ci * 1024);
        }
#pragma unroll
        for (int j2 = 0; j2 < CB; ++j2) {
            const int ci = w * CB + j2;
            const int row = ci * 16 + srow_in;
            async_load16(Bt + (size_t)(bn + row) * K + k0 + cg * 8, (char*)Bs[buf] + ci * 1024);
        }
    };

    const int nIter = Ksub / 32;
    stage(0, kbase);
    for (int kt = 0; kt < nIter; ++kt) {
        const int buf = kt & 1;
        __syncthreads();
        if (kt + 1 < nIter) stage(buf ^ 1, kbase + (kt + 1) * 32);

        short8 af[WM], bf[WN];
#pragma unroll
        for (int i = 0; i < WM; ++i) {
            const int ra = wy * (WM * 16) + i * 16 + c16;
            const int ca = quad ^ ((ra >> 2) & 3);
            af[i] = *(const short8*)((const char*)As[buf] + ra * 64 + ca * 16);
        }
#pragma unroll
        for (int i = 0; i < WN; ++i) {
            const int rb = wx * (WN * 16) + i * 16 + c16;
            const int cb = quad ^ ((rb >> 2) & 3);
            bf[i] = *(const short8*)((const char*)Bs[buf] + rb * 64 + cb * 16);
        }
#pragma unroll
        for (int mi = 0; mi < WM; ++mi)
#pragma unroll
            for (int ni = 0; ni < WN; ++ni)
                acc[mi][ni] = __builtin_amdgcn_mfma_f32_16x16x32_bf16(af[mi], bf[ni], acc[mi][ni], 0, 0, 0);
    }

    if (KSPLIT > 1) {
        OutT* Cp = C + (size_t)bzz * M * N;
#pragma unroll
        for (int mi = 0; mi < WM; ++mi)
#pragma unroll
            for (int ni = 0; ni < WN; ++ni) {
                const int n = bn + wx * (WN * 16) + ni * 16 + c16;
#pragma unroll
                for (int r = 0; r < 4; ++r) {
                    const int m = bm + wy * (WM * 16) + mi * 16 + quad * 4 + r;
                    if constexpr (sizeof(OutT) == 2)
                        Cp[(size_t)m * N + n] = __float2bfloat16(acc[mi][ni][r]);
                    else
                        Cp[(size_t)m * N + n] = acc[mi][ni][r];
                }
            }
        return;
    }

    if (SPLIT_QKV) {
        bf16* dst; int base;
        if (bn < 768)       { dst = QhOut; base = 0; }
        else if (bn < 1536) { dst = KhOut; base = 768; }
        else                { dst = VtOut; base = 1536; }
#pragma unroll
        for (int mi = 0; mi < WM; ++mi) {
#pragma unroll
            for (int ni = 0; ni < WN; ++ni) {
                const int nfull = bn + wx * (WN * 16) + ni * 16 + c16;
                const float bv = bias[nfull];
                const int nr = nfull - base;
                const int hv = nr >> 6, dv = nr & 63;
#pragma unroll
                for (int r = 0; r < 4; ++r) {
                    const int m = bm + wy * (WM * 16) + mi * 16 + quad * 4 + r;
                    const float v = acc[mi][ni][r] + bv;
                    const size_t bh = (size_t)((m >> 10) * HH + hv);
                    if (base == 1536)   // V: [b][h][d][s]
                        dst[(bh * DK + dv) * LL + (m & 1023)] = __float2bfloat16(v);
                    else                // Q/K: [b][h][s][d]
                        dst[(bh * LL + (m & 1023)) * DK + dv] = __float2bfloat16(v);
                }
            }
        }
        return;
    }

#pragma unroll
    for (int mi = 0; mi < WM; ++mi) {
#pragma unroll
        for (int ni = 0; ni < WN; ++ni) {
            const int n = bn + wx * (WN * 16) + ni * 16 + c16;
            const float bv = bias[n];
#pragma unroll
            for (int r = 0; r < 4; ++r) {
                const int m = bm + wy * (WM * 16) + mi * 16 + quad * 4 + r;
                float v = acc[mi][ni][r] + bv;
                if (GELU) v = 0.5f * v * (1.f + erff(v * 0.70710678118f));
                if (RES == 2) v += res[(size_t)m * N + n];
                if constexpr (sizeof(OutT) == 2)
                    C[(size_t)m * N + n] = __float2bfloat16(v);
                else
                    C[(size_t)m * N + n] = v;
            }
        }
    }
}

// ---------------- Flash attention: pipelined staging (K double-buffered, V phase-split) ----------------
// Session-verified best. Elimination record (r3..r11): DMA-latency cover, barrier halving,
// in-wave ILP reorder all NEUTRAL; per-wave global K/V loads (-58us), conflicting vector
// P-transpose (-22us), VMEM table gathers (-49us) all WORSE. Measured local optimum.
__global__ __launch_bounds__(256) void flash_attn_kernel(
        const bf16* __restrict__ Qh, const bf16* __restrict__ Kh, const bf16* __restrict__ Vt,
        const int* __restrict__ postag, const float* __restrict__ lex,
        const float* __restrict__ rel_emb, const float* __restrict__ pt_table,
        bf16* __restrict__ O) {
    const int qt = blockIdx.x;
    const int h  = blockIdx.y;
    const int b  = blockIdx.z;
    const int tid  = threadIdx.x;
    const int w    = tid >> 6;
    const int lane = tid & 63;
    const int c    = lane & 15;
    const int quad = lane >> 4;

    __shared__ short Ks[2][4096];       // double-buffered K tile (2 x 8KB)
    __shared__ short Vs[4096];          // single V tile (8KB)
    __shared__ bf16  Ps[4][16][72];
    __shared__ f32x4 relT[516];
    __shared__ float pt_col[1024];
    __shared__ float lex_f[LL];
    __shared__ short ps_f[LL];
    // LDS total: 16384+8192+9216+8256+4096+4096+2048 = 52288 B -> 3 blocks/CU (limit 53333)

    for (int i = tid; i < 516; i += 256) {
        f32x4 t;
        t[0] = rel_emb[min(i, 512) * HH + h];
        t[1] = rel_emb[min(max(i - 1, 0), 512) * HH + h];
        t[2] = rel_emb[min(max(i - 2, 0), 512) * HH + h];
        t[3] = rel_emb[min(max(i - 3, 0), 512) * HH + h];
        relT[i] = t;
    }
    for (int i = tid; i < 1024; i += 256) {
        pt_col[i] = pt_table[i * HH + h];
        lex_f[i]  = lex[b * LL + i];
        ps_f[i]   = (short)postag[b * LL + i];
    }

    const int q0 = qt * 64 + w * 16;
    const size_t bh = (size_t)(b * HH + h);
    const bf16* Kbase = Kh + bh * LL * DK;
    const bf16* Vbase = Vt + bh * DK * LL;

    const int srow = lane >> 3;
    const int schunk = lane & 7;

    // prologue: stage K(0) -> Ks[0]
#pragma unroll
    for (int j = 0; j < 2; ++j) {
        const int row = w * 16 + j * 8 + srow;
        const int g = schunk ^ (row & 7);
        async_load16(Kbase + (size_t)row * DK + g * 8,
                     (char*)Ks[0] + (w * 16 + j * 8) * 128);
    }

    short8 qf0, qf1;
    {
        const bf16* qp = Qh + (bh * LL + q0 + c) * DK + quad * 8;
        qf0 = *(const short8*)qp;
        qf1 = *(const short8*)(qp + 32);
    }
    int plx_r[4];
#pragma unroll
    for (int r = 0; r < 4; ++r) plx_r[r] = postag[b * LL + q0 + quad * 4 + r] * PP;

    f32x4 o_acc[4];
#pragma unroll
    for (int t = 0; t < 4; ++t) o_acc[t] = (f32x4)0.f;
    float lsum[4] = {0.f, 0.f, 0.f, 0.f};

    __syncthreads();   // drains K(0); LDS tables visible

    for (int tt = 0; tt < LL / 64; ++tt) {
        const int s0 = tt * 64;
        const int cur = tt & 1;
        const short* Kc = Ks[cur];

        // issue V(tt) -> Vs (write-safe: all waves past previous endsync)
#pragma unroll
        for (int j = 0; j < 2; ++j) {
            const int row = w * 16 + j * 8 + srow;
            const int g = schunk ^ (row & 7);
            async_load16(Vbase + (size_t)row * LL + s0 + g * 8,
                         (char*)Vs + (w * 16 + j * 8) * 128);
        }

        // ---- Phase 1: QK^T on Ks[cur] + softmax + Ps (no Vs dependency) ----
        f32x4 S[4];
#pragma unroll
        for (int t = 0; t < 4; ++t) {
            const int r = t * 16 + c;
            short8 kf0 = *(const short8*)&Kc[r * 64 + ((quad ^ (r & 7)) * 8)];
            short8 kf1 = *(const short8*)&Kc[r * 64 + (((4 + quad) ^ (r & 7)) * 8)];
            f32x4 a = (f32x4)0.f;
            a = __builtin_amdgcn_mfma_f32_16x16x32_bf16(qf0, kf0, a, 0, 0, 0);
            a = __builtin_amdgcn_mfma_f32_16x16x32_bf16(qf1, kf1, a, 0, 0, 0);
            S[t] = a;
        }

        const int d0 = s0 - q0;
        if (d0 >= 271 || d0 <= -319) {
            const float rcv = (d0 >= 271) ? relT[515][0] : relT[0][0];
#pragma unroll
            for (int t = 0; t < 4; ++t) {
                const int s_glob = s0 + t * 16 + c;
                const float lx = lex_f[s_glob] + rcv;
                const int   ps = ps_f[s_glob];
#pragma unroll
                for (int r = 0; r < 4; ++r) {
                    float e = __expf(S[t][r] * 0.125f + pt_col[plx_r[r] + ps] + lx);
                    S[t][r] = e;
                    lsum[r] += e;
                }
            }
        } else {
            const int ebase = d0 - quad * 4 + 256;
#pragma unroll
            for (int t = 0; t < 4; ++t) {
                const int s_loc = t * 16 + c;
                const int s_glob = s0 + s_loc;
                const float lx = lex_f[s_glob];
                const int   ps = ps_f[s_glob];
                const int e = min(max(ebase + s_loc, 0), 515);
                f32x4 rv = relT[e];
#pragma unroll
                for (int r = 0; r < 4; ++r) {
                    float ev = __expf(S[t][r] * 0.125f + rv[r] + pt_col[plx_r[r] + ps] + lx);
                    S[t][r] = ev;
                    lsum[r] += ev;
                }
            }
        }

#pragma unroll
        for (int t = 0; t < 4; ++t)
#pragma unroll
            for (int r = 0; r < 4; ++r)
                Ps[w][quad * 4 + r][t * 16 + c] = __float2bfloat16(S[t][r]);

        short8 pa0 = *(const short8*)&Ps[w][c][quad * 8];
        short8 pa1 = *(const short8*)&Ps[w][c][quad * 8 + 32];

        __syncthreads();   // midsync: drains V(tt) (covered by Phase 1)

        // issue K(tt+1) -> Ks[cur^1] (write-safe: its readers finished before prev midsync)
        if (tt + 1 < LL / 64) {
#pragma unroll
            for (int j = 0; j < 2; ++j) {
                const int row = w * 16 + j * 8 + srow;
                const int g = schunk ^ (row & 7);
                async_load16(Kbase + (size_t)(s0 + 64 + row) * DK + g * 8,
                             (char*)Ks[cur ^ 1] + (w * 16 + j * 8) * 128);
            }
        }

        // ---- Phase 2: PV on Vs ----
#pragma unroll
        for (int t = 0; t < 4; ++t) {
            const int r = t * 16 + c;
            short8 vf0 = *(const short8*)&Vs[r * 64 + ((quad ^ (r & 7)) * 8)];
            short8 vf1 = *(const short8*)&Vs[r * 64 + (((4 + quad) ^ (r & 7)) * 8)];
            o_acc[t] = __builtin_amdgcn_mfma_f32_16x16x32_bf16(pa0, vf0, o_acc[t], 0, 0, 0);
            o_acc[t] = __builtin_amdgcn_mfma_f32_16x16x32_bf16(pa1, vf1, o_acc[t], 0, 0, 0);
        }

        __syncthreads();   // endsync: drains K(tt+1) (covered by Phase 2); protects Vs overwrite
    }

#pragma unroll
    for (int mm = 1; mm < 16; mm <<= 1)
#pragma unroll
        for (int r = 0; r < 4; ++r) lsum[r] += __shfl_xor(lsum[r], mm);

    float inv_l[4];
#pragma unroll
    for (int r = 0; r < 4; ++r) inv_l[r] = 1.f / lsum[r];
#pragma unroll
    for (int t = 0; t < 4; ++t)
#pragma unroll
        for (int r = 0; r < 4; ++r) {
            const int row = q0 + quad * 4 + r;
            O[((size_t)(b * LL + row)) * DD + h * DK + t * 16 + c] =
                __float2bfloat16(o_acc[t][r] * inv_l[r]);
        }
}

extern "C" void kernel_launch(void* const* d_in, const int* in_sizes, int n_in,
                              void* d_out, int out_size, void* d_ws, size_t ws_size,
                              hipStream_t stream) {
    const float* x          = (const float*)d_in[0];
    const int*   postag_ids = (const int*)d_in[1];
    const float* lex_mask   = (const float*)d_in[2];
    const float* ln1_g      = (const float*)d_in[3];
    const float* ln1_b      = (const float*)d_in[4];
    const float* Wq         = (const float*)d_in[5];
    const float* bq         = (const float*)d_in[6];
    const float* Wk         = (const float*)d_in[7];
    const float* bk         = (const float*)d_in[8];
    const float* Wv         = (const float*)d_in[9];
    const float* bv         = (const float*)d_in[10];
    const float* Wo         = (const float*)d_in[11];
    const float* bo         = (const float*)d_in[12];
    const float* rel_emb    = (const float*)d_in[13];
    const float* pt_table   = (const float*)d_in[14];
    const float* ln2_g      = (const float*)d_in[15];
    const float* ln2_b      = (const float*)d_in[16];
    const float* W1         = (const float*)d_in[17];
    const float* b1         = (const float*)d_in[18];
    const float* W2         = (const float*)d_in[19];
    const float* b2         = (const float*)d_in[20];

    const int M = BB * LL;            // 4096
    char* ws = (char*)d_ws;
    size_t off = 0;
    // y_ln..Vt (25.17MB) is reused as the FF2 bf16 split-K4 partial buffer.
    bf16* y_ln  = (bf16*)(ws + off); off += (size_t)M * DD * 2;
    bf16* Qh    = (bf16*)(ws + off); off += (size_t)M * DD * 2;
    bf16* Kh    = (bf16*)(ws + off); off += (size_t)M * DD * 2;
    bf16* Vt    = (bf16*)(ws + off); off += (size_t)M * DD * 2;
    bf16* attn  = (bf16*)(ws + off); off += (size_t)M * DD * 2;
    bf16* h2    = (bf16*)(ws + off); off += (size_t)M * DD * 2;
    float* out1 = (float*)(ws + off); off += (size_t)M * DD * 4;
    bf16* ff1   = (bf16*)(ws + off); off += (size_t)M * FF_ * 2;
    bf16* WtQKV = (bf16*)(ws + off); off += (size_t)2304 * DD * 2;
    bf16* WtO   = (bf16*)(ws + off); off += (size_t)DD * DD * 2;
    bf16* Wt1   = (bf16*)(ws + off); off += (size_t)FF_ * DD * 2;
    bf16* Wt2   = (bf16*)(ws + off); off += (size_t)DD * FF_ * 2;
    float* bqkv = (float*)(ws + off); off += (size_t)2304 * 4;
    bf16*  PartF2 = (bf16*)ws;    // [4][M][DD] bf16 == y_ln..Vt region

    // 0+1. LN1 + weight transposes + bias pack
    prep_ln<<<11017, 256, 0, stream>>>(x, ln1_g, ln1_b, Wq, Wk, Wv, Wo, W1, W2,
                                       bq, bk, bv, y_ln, WtQKV, WtO, Wt1, Wt2, bqkv);

    // 2. fused QKV projection, 64x128 tiles (1152 blocks, 4.5/CU)
    mfma_gemm_bt<64, 128, 0, false, true, 1, bf16><<<dim3(2304 / 128, M / 64), 256, 0, stream>>>(
        y_ln, WtQKV, bqkv, nullptr, (bf16*)nullptr, Qh, Kh, Vt, M, 2304, DD);

    // 3. flash attention
    flash_attn_kernel<<<dim3(LL / 64, HH, BB), 256, 0, stream>>>(
        Qh, Kh, Vt, postag_ids, lex_mask, rel_emb, pt_table, attn);

    // 4. Wo projection, 64x64 tiles (768 blocks, 3/CU), unsplit, fused +bo +x -> out1 fp32
    mfma_gemm_bt<64, 64, 2, false, false, 1, float><<<dim3(DD / 64, M / 64), 256, 0, stream>>>(
        attn, WtO, bo, x, out1, nullptr, nullptr, nullptr, M, DD, DD);

    // 5. LN2 (plain apply on out1)
    ln_kernel<<<M, 256, 0, stream>>>(out1, ln2_g, ln2_b, 1e-5f, h2);

    // 6. FF1 + exact GELU, 64x128 tiles (1536 blocks, 6/CU; was 128x128 @ 3/CU, 70us @ 276TF)
    mfma_gemm_bt<64, 128, 0, true, false, 1, bf16><<<dim3(FF_ / 128, M / 64), 256, 0, stream>>>(
        h2, Wt1, b1, nullptr, ff1, nullptr, nullptr, nullptr, M, FF_, DD);

    // 7. FF2 split-K=4, bf16 partials, 64x128 tiles (1536 blocks, 6/CU)
    mfma_gemm_bt<64, 128, 0, false, false, 4, bf16><<<dim3(DD / 128, M / 64, 4), 256, 0, stream>>>(
        ff1, Wt2, nullptr, nullptr, PartF2, nullptr, nullptr, nullptr, M, DD, FF_);

    // 8. FF2 reduce + b2 + out1 residual -> d_out
    ff2_reduce<<<(M * DD / 8) / 256, 256, 0, stream>>>(PartF2, out1, b2, (float*)d_out);
}

// Round 15
// 289.767 us; speedup vs baseline: 1.0712x; 1.0712x over previous
//
#include <hip/hip_runtime.h>
#include <hip/hip_bf16.h>
#include <math.h>

typedef __hip_bfloat16 bf16;
typedef __attribute__((ext_vector_type(8))) short short8;
typedef __attribute__((ext_vector_type(4))) float f32x4;

#define BB 4
#define LL 1024
#define DD 768
#define HH 12
#define DK 64
#define FF_ 3072
#define PP 32
#define MAXD 256

// async global->LDS, 16B per lane. LDS dest: wave-uniform base + lane*16.
__device__ __forceinline__ void async_load16(const void* g, void* l) {
    __builtin_amdgcn_global_load_lds(
        (const __attribute__((address_space(1))) unsigned int*)g,
        (__attribute__((address_space(3))) unsigned int*)l, 16, 0, 0);
}

// ---------------- LayerNorm (fp32 in, bf16 out) ----------------
__global__ __launch_bounds__(256) void ln_kernel(const float* __restrict__ x,
                                                 const float* __restrict__ g,
                                                 const float* __restrict__ b,
                                                 float eps,
                                                 bf16* __restrict__ y) {
    const int row = blockIdx.x;
    const int tid = threadIdx.x;
    const float* xr = x + (size_t)row * DD;

    float v[3];
    float s = 0.f, ss = 0.f;
#pragma unroll
    for (int i = 0; i < 3; ++i) {
        float t = xr[tid + i * 256];
        v[i] = t; s += t; ss += t * t;
    }
    __shared__ float rs[256], rss[256];
    rs[tid] = s; rss[tid] = ss;
    __syncthreads();
    for (int off = 128; off; off >>= 1) {
        if (tid < off) { rs[tid] += rs[tid + off]; rss[tid] += rss[tid + off]; }
        __syncthreads();
    }
    const float mean = rs[0] * (1.f / DD);
    const float var  = rss[0] * (1.f / DD) - mean * mean;
    const float inv  = rsqrtf(var + eps);
#pragma unroll
    for (int i = 0; i < 3; ++i) {
        int c = tid + i * 256;
        y[(size_t)row * DD + c] = __float2bfloat16((v[i] - mean) * inv * g[c] + b[c]);
    }
}

// ---------------- fused: LN1 + all weight transposes + bias pack ----------------
__global__ __launch_bounds__(256) void prep_ln(
        const float* __restrict__ x,
        const float* __restrict__ ln1_g, const float* __restrict__ ln1_b,
        const float* __restrict__ Wq, const float* __restrict__ Wk,
        const float* __restrict__ Wv, const float* __restrict__ Wo,
        const float* __restrict__ W1, const float* __restrict__ W2,
        const float* __restrict__ bq, const float* __restrict__ bk,
        const float* __restrict__ bv,
        bf16* __restrict__ y_ln,
        bf16* __restrict__ WtQKV, bf16* __restrict__ WtO,
        bf16* __restrict__ Wt1, bf16* __restrict__ Wt2,
        float* __restrict__ bqkv) {
    const int bid = blockIdx.x;
    const int tid = threadIdx.x;

    if (bid < 4096) {                       // ---- LN1 ----
        const float* xr = x + (size_t)bid * DD;
        float v[3];
        float s = 0.f, ss = 0.f;
#pragma unroll
        for (int i = 0; i < 3; ++i) {
            float t = xr[tid + i * 256];
            v[i] = t; s += t; ss += t * t;
        }
        __shared__ float rs[256], rss[256];
        rs[tid] = s; rss[tid] = ss;
        __syncthreads();
        for (int off = 128; off; off >>= 1) {
            if (tid < off) { rs[tid] += rs[tid + off]; rss[tid] += rss[tid + off]; }
            __syncthreads();
        }
        const float mean = rs[0] * (1.f / DD);
        const float var  = rss[0] * (1.f / DD) - mean * mean;
        const float inv  = rsqrtf(var + 1e-6f);
#pragma unroll
        for (int i = 0; i < 3; ++i) {
            int c = tid + i * 256;
            y_ln[(size_t)bid * DD + c] = __float2bfloat16((v[i] - mean) * inv * ln1_g[c] + ln1_b[c]);
        }
        return;
    }
    if (bid >= 11008) {                     // ---- bias pack ----
        int i = (bid - 11008) * 256 + tid;
        if (i < 2304) {
            float v = (i < 768) ? bq[i] : (i < 1536) ? bk[i - 768] : bv[i - 1536];
            bqkv[i] = v;
        }
        return;
    }
    // ---- transposes ----
    const int tb = bid - 4096;
    const float* W; bf16* Wt; int K, N, tile;
    if (tb < 576)       { W = Wq; Wt = WtQKV;                      K = DD;  N = DD;  tile = tb; }
    else if (tb < 1152) { W = Wk; Wt = WtQKV + (size_t)768 * DD;   K = DD;  N = DD;  tile = tb - 576; }
    else if (tb < 1728) { W = Wv; Wt = WtQKV + (size_t)1536 * DD;  K = DD;  N = DD;  tile = tb - 1152; }
    else if (tb < 2304) { W = Wo; Wt = WtO;                        K = DD;  N = DD;  tile = tb - 1728; }
    else if (tb < 4608) { W = W1; Wt = Wt1;                        K = DD;  N = FF_; tile = tb - 2304; }
    else                { W = W2; Wt = Wt2;                        K = FF_; N = DD;  tile = tb - 4608; }
    const int ntn = N / 32;
    const int n0 = (tile % ntn) * 32, k0 = (tile / ntn) * 32;

    __shared__ float tilebuf[32][33];
    const int tx = tid & 31, ty = tid >> 5;
#pragma unroll
    for (int i = 0; i < 4; ++i) {
        int k = ty + i * 8;
        tilebuf[k][tx] = W[(size_t)(k0 + k) * N + n0 + tx];
    }
    __syncthreads();
#pragma unroll
    for (int i = 0; i < 4; ++i) {
        int n = ty + i * 8;
        Wt[(size_t)(n0 + n) * K + k0 + tx] = __float2bfloat16(tilebuf[tx][n]);
    }
}

// ---------------- FF2 split-K(4, bf16 partials) reduce + bias + out1 residual ----------------
__global__ __launch_bounds__(256) void ff2_reduce(const bf16* __restrict__ Fp,
                                                  const float* __restrict__ out1,
                                                  const float* __restrict__ b2,
                                                  float* __restrict__ dout) {
    const size_t stride = (size_t)BB * LL * DD;
    const size_t i8 = ((size_t)blockIdx.x * 256 + threadIdx.x) * 8;
    const int c = (int)(i8 % DD);

    float acc[8];
    float4 r0 = *(const float4*)(out1 + i8);
    float4 r1 = *(const float4*)(out1 + i8 + 4);
    float4 bb0 = *(const float4*)(b2 + c);
    float4 bb1 = *(const float4*)(b2 + c + 4);
    acc[0] = r0.x + bb0.x; acc[1] = r0.y + bb0.y; acc[2] = r0.z + bb0.z; acc[3] = r0.w + bb0.w;
    acc[4] = r1.x + bb1.x; acc[5] = r1.y + bb1.y; acc[6] = r1.z + bb1.z; acc[7] = r1.w + bb1.w;
#pragma unroll
    for (int p = 0; p < 4; ++p) {
        short8 v = *(const short8*)(Fp + p * stride + i8);
#pragma unroll
        for (int k = 0; k < 8; ++k) acc[k] += __bfloat162float(((const bf16*)&v)[k]);
    }
    float4 o0 = {acc[0], acc[1], acc[2], acc[3]};
    float4 o1 = {acc[4], acc[5], acc[6], acc[7]};
    *(float4*)(dout + i8) = o0;
    *(float4*)(dout + i8 + 4) = o1;
}

// ---------------- MFMA GEMM: templated TMxTN tile, dbuf LDS, XCD-swizzled, split-K ----------------
// C = act(A @ Bt^T + bias) (+res). BK=32. waves 2x2; wave frag block (TM/2)x(TN/2).
// Grid must satisfy gridDim.y*gridDim.z % 8 == 0 for the XCD swizzle.
// Tile-size note (r13/r14 measured): FF1/FF2 at 64x128 raise occupancy 32->46% and MfmaUtil
// 10->14 but add +50% HBM traffic/dispatch (B-panel re-reads) -> total REGRESSES 290->310.
// 128x128 is the measured traffic/occupancy equilibrium for these shapes.
template <int TM, int TN, int RES, bool GELU, bool SPLIT_QKV, int KSPLIT, typename OutT>
__global__ __launch_bounds__(256) void mfma_gemm_bt(const bf16* __restrict__ A,
                                                    const bf16* __restrict__ Bt,
                                                    const float* __restrict__ bias,
                                                    const float* __restrict__ res,
                                                    OutT* __restrict__ C,
                                                    bf16* __restrict__ QhOut,
                                                    bf16* __restrict__ KhOut,
                                                    bf16* __restrict__ VtOut,
                                                    int M, int N, int K) {
    constexpr int WM = TM / 32;      // m-frags per wave
    constexpr int WN = TN / 32;      // n-frags per wave
    constexpr int CA = TM / 64;      // A staging instrs per wave
    constexpr int CB = TN / 64;
    __shared__ short As[2][TM * 32];
    __shared__ short Bs[2][TN * 32];

    const int L = blockIdx.x + gridDim.x * (blockIdx.y + gridDim.y * blockIdx.z);
    const int xcd = L & 7, j = L >> 3;
    const int col = j % gridDim.x;
    const int panel = xcd + 8 * (j / gridDim.x);
    const int byy = panel % gridDim.y;
    const int bzz = panel / gridDim.y;

    const int bm = byy * TM, bn = col * TN;
    const int tid = threadIdx.x;
    const int w = tid >> 6, lane = tid & 63;
    const int c16 = lane & 15, quad = lane >> 4;
    const int wy = w >> 1, wx = w & 1;

    const int srow_in = lane >> 2;
    const int cg = (lane & 3) ^ quad;

    const int Ksub = K / KSPLIT;
    const int kbase = bzz * Ksub;

    f32x4 acc[WM][WN];
#pragma unroll
    for (int i = 0; i < WM; ++i)
#pragma unroll
        for (int j2 = 0; j2 < WN; ++j2) acc[i][j2] = (f32x4)0.f;

    auto stage = [&](int buf, int k0) {
#pragma unroll
        for (int j2 = 0; j2 < CA; ++j2) {
            const int ci = w * CA + j2;
            const int row = ci * 16 + srow_in;
            async_load16(A + (size_t)(bm + row) * K + k0 + cg * 8, (char*)As[buf] + ci * 1024);
        }
#pragma unroll
        for (int j2 = 0; j2 < CB; ++j2) {
            const int ci = w * CB + j2;
            const int row = ci * 16 + srow_in;
            async_load16(Bt + (size_t)(bn + row) * K + k0 + cg * 8, (char*)Bs[buf] + ci * 1024);
        }
    };

    const int nIter = Ksub / 32;
    stage(0, kbase);
    for (int kt = 0; kt < nIter; ++kt) {
        const int buf = kt & 1;
        __syncthreads();
        if (kt + 1 < nIter) stage(buf ^ 1, kbase + (kt + 1) * 32);

        short8 af[WM], bf[WN];
#pragma unroll
        for (int i = 0; i < WM; ++i) {
            const int ra = wy * (WM * 16) + i * 16 + c16;
            const int ca = quad ^ ((ra >> 2) & 3);
            af[i] = *(const short8*)((const char*)As[buf] + ra * 64 + ca * 16);
        }
#pragma unroll
        for (int i = 0; i < WN; ++i) {
            const int rb = wx * (WN * 16) + i * 16 + c16;
            const int cb = quad ^ ((rb >> 2) & 3);
            bf[i] = *(const short8*)((const char*)Bs[buf] + rb * 64 + cb * 16);
        }
#pragma unroll
        for (int mi = 0; mi < WM; ++mi)
#pragma unroll
            for (int ni = 0; ni < WN; ++ni)
                acc[mi][ni] = __builtin_amdgcn_mfma_f32_16x16x32_bf16(af[mi], bf[ni], acc[mi][ni], 0, 0, 0);
    }

    if (KSPLIT > 1) {
        OutT* Cp = C + (size_t)bzz * M * N;
#pragma unroll
        for (int mi = 0; mi < WM; ++mi)
#pragma unroll
            for (int ni = 0; ni < WN; ++ni) {
                const int n = bn + wx * (WN * 16) + ni * 16 + c16;
#pragma unroll
                for (int r = 0; r < 4; ++r) {
                    const int m = bm + wy * (WM * 16) + mi * 16 + quad * 4 + r;
                    if constexpr (sizeof(OutT) == 2)
                        Cp[(size_t)m * N + n] = __float2bfloat16(acc[mi][ni][r]);
                    else
                        Cp[(size_t)m * N + n] = acc[mi][ni][r];
                }
            }
        return;
    }

    if (SPLIT_QKV) {
        bf16* dst; int base;
        if (bn < 768)       { dst = QhOut; base = 0; }
        else if (bn < 1536) { dst = KhOut; base = 768; }
        else                { dst = VtOut; base = 1536; }
#pragma unroll
        for (int mi = 0; mi < WM; ++mi) {
#pragma unroll
            for (int ni = 0; ni < WN; ++ni) {
                const int nfull = bn + wx * (WN * 16) + ni * 16 + c16;
                const float bv = bias[nfull];
                const int nr = nfull - base;
                const int hv = nr >> 6, dv = nr & 63;
#pragma unroll
                for (int r = 0; r < 4; ++r) {
                    const int m = bm + wy * (WM * 16) + mi * 16 + quad * 4 + r;
                    const float v = acc[mi][ni][r] + bv;
                    const size_t bh = (size_t)((m >> 10) * HH + hv);
                    if (base == 1536)   // V: [b][h][d][s]
                        dst[(bh * DK + dv) * LL + (m & 1023)] = __float2bfloat16(v);
                    else                // Q/K: [b][h][s][d]
                        dst[(bh * LL + (m & 1023)) * DK + dv] = __float2bfloat16(v);
                }
            }
        }
        return;
    }

#pragma unroll
    for (int mi = 0; mi < WM; ++mi) {
#pragma unroll
        for (int ni = 0; ni < WN; ++ni) {
            const int n = bn + wx * (WN * 16) + ni * 16 + c16;
            const float bv = bias[n];
#pragma unroll
            for (int r = 0; r < 4; ++r) {
                const int m = bm + wy * (WM * 16) + mi * 16 + quad * 4 + r;
                float v = acc[mi][ni][r] + bv;
                if (GELU) v = 0.5f * v * (1.f + erff(v * 0.70710678118f));
                if (RES == 2) v += res[(size_t)m * N + n];
                if constexpr (sizeof(OutT) == 2)
                    C[(size_t)m * N + n] = __float2bfloat16(v);
                else
                    C[(size_t)m * N + n] = v;
            }
        }
    }
}

// ---------------- Flash attention: pipelined staging (K double-buffered, V phase-split) ----------------
// Session-verified best. Elimination record (r3..r11): DMA-latency cover, barrier halving,
// in-wave ILP reorder all NEUTRAL; per-wave global K/V loads (-58us), conflicting vector
// P-transpose (-22us), VMEM table gathers (-49us) all WORSE. Measured local optimum.
__global__ __launch_bounds__(256) void flash_attn_kernel(
        const bf16* __restrict__ Qh, const bf16* __restrict__ Kh, const bf16* __restrict__ Vt,
        const int* __restrict__ postag, const float* __restrict__ lex,
        const float* __restrict__ rel_emb, const float* __restrict__ pt_table,
        bf16* __restrict__ O) {
    const int qt = blockIdx.x;
    const int h  = blockIdx.y;
    const int b  = blockIdx.z;
    const int tid  = threadIdx.x;
    const int w    = tid >> 6;
    const int lane = tid & 63;
    const int c    = lane & 15;
    const int quad = lane >> 4;

    __shared__ short Ks[2][4096];       // double-buffered K tile (2 x 8KB)
    __shared__ short Vs[4096];          // single V tile (8KB)
    __shared__ bf16  Ps[4][16][72];
    __shared__ f32x4 relT[516];
    __shared__ float pt_col[1024];
    __shared__ float lex_f[LL];
    __shared__ short ps_f[LL];
    // LDS total: 16384+8192+9216+8256+4096+4096+2048 = 52288 B -> 3 blocks/CU (limit 53333)

    for (int i = tid; i < 516; i += 256) {
        f32x4 t;
        t[0] = rel_emb[min(i, 512) * HH + h];
        t[1] = rel_emb[min(max(i - 1, 0), 512) * HH + h];
        t[2] = rel_emb[min(max(i - 2, 0), 512) * HH + h];
        t[3] = rel_emb[min(max(i - 3, 0), 512) * HH + h];
        relT[i] = t;
    }
    for (int i = tid; i < 1024; i += 256) {
        pt_col[i] = pt_table[i * HH + h];
        lex_f[i]  = lex[b * LL + i];
        ps_f[i]   = (short)postag[b * LL + i];
    }

    const int q0 = qt * 64 + w * 16;
    const size_t bh = (size_t)(b * HH + h);
    const bf16* Kbase = Kh + bh * LL * DK;
    const bf16* Vbase = Vt + bh * DK * LL;

    const int srow = lane >> 3;
    const int schunk = lane & 7;

    // prologue: stage K(0) -> Ks[0]
#pragma unroll
    for (int j = 0; j < 2; ++j) {
        const int row = w * 16 + j * 8 + srow;
        const int g = schunk ^ (row & 7);
        async_load16(Kbase + (size_t)row * DK + g * 8,
                     (char*)Ks[0] + (w * 16 + j * 8) * 128);
    }

    short8 qf0, qf1;
    {
        const bf16* qp = Qh + (bh * LL + q0 + c) * DK + quad * 8;
        qf0 = *(const short8*)qp;
        qf1 = *(const short8*)(qp + 32);
    }
    int plx_r[4];
#pragma unroll
    for (int r = 0; r < 4; ++r) plx_r[r] = postag[b * LL + q0 + quad * 4 + r] * PP;

    f32x4 o_acc[4];
#pragma unroll
    for (int t = 0; t < 4; ++t) o_acc[t] = (f32x4)0.f;
    float lsum[4] = {0.f, 0.f, 0.f, 0.f};

    __syncthreads();   // drains K(0); LDS tables visible

    for (int tt = 0; tt < LL / 64; ++tt) {
        const int s0 = tt * 64;
        const int cur = tt & 1;
        const short* Kc = Ks[cur];

        // issue V(tt) -> Vs (write-safe: all waves past previous endsync)
#pragma unroll
        for (int j = 0; j < 2; ++j) {
            const int row = w * 16 + j * 8 + srow;
            const int g = schunk ^ (row & 7);
            async_load16(Vbase + (size_t)row * LL + s0 + g * 8,
                         (char*)Vs + (w * 16 + j * 8) * 128);
        }

        // ---- Phase 1: QK^T on Ks[cur] + softmax + Ps (no Vs dependency) ----
        f32x4 S[4];
#pragma unroll
        for (int t = 0; t < 4; ++t) {
            const int r = t * 16 + c;
            short8 kf0 = *(const short8*)&Kc[r * 64 + ((quad ^ (r & 7)) * 8)];
            short8 kf1 = *(const short8*)&Kc[r * 64 + (((4 + quad) ^ (r & 7)) * 8)];
            f32x4 a = (f32x4)0.f;
            a = __builtin_amdgcn_mfma_f32_16x16x32_bf16(qf0, kf0, a, 0, 0, 0);
            a = __builtin_amdgcn_mfma_f32_16x16x32_bf16(qf1, kf1, a, 0, 0, 0);
            S[t] = a;
        }

        const int d0 = s0 - q0;
        if (d0 >= 271 || d0 <= -319) {
            const float rcv = (d0 >= 271) ? relT[515][0] : relT[0][0];
#pragma unroll
            for (int t = 0; t < 4; ++t) {
                const int s_glob = s0 + t * 16 + c;
                const float lx = lex_f[s_glob] + rcv;
                const int   ps = ps_f[s_glob];
#pragma unroll
                for (int r = 0; r < 4; ++r) {
                    float e = __expf(S[t][r] * 0.125f + pt_col[plx_r[r] + ps] + lx);
                    S[t][r] = e;
                    lsum[r] += e;
                }
            }
        } else {
            const int ebase = d0 - quad * 4 + 256;
#pragma unroll
            for (int t = 0; t < 4; ++t) {
                const int s_loc = t * 16 + c;
                const int s_glob = s0 + s_loc;
                const float lx = lex_f[s_glob];
                const int   ps = ps_f[s_glob];
                const int e = min(max(ebase + s_loc, 0), 515);
                f32x4 rv = relT[e];
#pragma unroll
                for (int r = 0; r < 4; ++r) {
                    float ev = __expf(S[t][r] * 0.125f + rv[r] + pt_col[plx_r[r] + ps] + lx);
                    S[t][r] = ev;
                    lsum[r] += ev;
                }
            }
        }

#pragma unroll
        for (int t = 0; t < 4; ++t)
#pragma unroll
            for (int r = 0; r < 4; ++r)
                Ps[w][quad * 4 + r][t * 16 + c] = __float2bfloat16(S[t][r]);

        short8 pa0 = *(const short8*)&Ps[w][c][quad * 8];
        short8 pa1 = *(const short8*)&Ps[w][c][quad * 8 + 32];

        __syncthreads();   // midsync: drains V(tt) (covered by Phase 1)

        // issue K(tt+1) -> Ks[cur^1] (write-safe: its readers finished before prev midsync)
        if (tt + 1 < LL / 64) {
#pragma unroll
            for (int j = 0; j < 2; ++j) {
                const int row = w * 16 + j * 8 + srow;
                const int g = schunk ^ (row & 7);
                async_load16(Kbase + (size_t)(s0 + 64 + row) * DK + g * 8,
                             (char*)Ks[cur ^ 1] + (w * 16 + j * 8) * 128);
            }
        }

        // ---- Phase 2: PV on Vs ----
#pragma unroll
        for (int t = 0; t < 4; ++t) {
            const int r = t * 16 + c;
            short8 vf0 = *(const short8*)&Vs[r * 64 + ((quad ^ (r & 7)) * 8)];
            short8 vf1 = *(const short8*)&Vs[r * 64 + (((4 + quad) ^ (r & 7)) * 8)];
            o_acc[t] = __builtin_amdgcn_mfma_f32_16x16x32_bf16(pa0, vf0, o_acc[t], 0, 0, 0);
            o_acc[t] = __builtin_amdgcn_mfma_f32_16x16x32_bf16(pa1, vf1, o_acc[t], 0, 0, 0);
        }

        __syncthreads();   // endsync: drains K(tt+1) (covered by Phase 2); protects Vs overwrite
    }

#pragma unroll
    for (int mm = 1; mm < 16; mm <<= 1)
#pragma unroll
        for (int r = 0; r < 4; ++r) lsum[r] += __shfl_xor(lsum[r], mm);

    float inv_l[4];
#pragma unroll
    for (int r = 0; r < 4; ++r) inv_l[r] = 1.f / lsum[r];
#pragma unroll
    for (int t = 0; t < 4; ++t)
#pragma unroll
        for (int r = 0; r < 4; ++r) {
            const int row = q0 + quad * 4 + r;
            O[((size_t)(b * LL + row)) * DD + h * DK + t * 16 + c] =
                __float2bfloat16(o_acc[t][r] * inv_l[r]);
        }
}

extern "C" void kernel_launch(void* const* d_in, const int* in_sizes, int n_in,
                              void* d_out, int out_size, void* d_ws, size_t ws_size,
                              hipStream_t stream) {
    const float* x          = (const float*)d_in[0];
    const int*   postag_ids = (const int*)d_in[1];
    const float* lex_mask   = (const float*)d_in[2];
    const float* ln1_g      = (const float*)d_in[3];
    const float* ln1_b      = (const float*)d_in[4];
    const float* Wq         = (const float*)d_in[5];
    const float* bq         = (const float*)d_in[6];
    const float* Wk         = (const float*)d_in[7];
    const float* bk         = (const float*)d_in[8];
    const float* Wv         = (const float*)d_in[9];
    const float* bv         = (const float*)d_in[10];
    const float* Wo         = (const float*)d_in[11];
    const float* bo         = (const float*)d_in[12];
    const float* rel_emb    = (const float*)d_in[13];
    const float* pt_table   = (const float*)d_in[14];
    const float* ln2_g      = (const float*)d_in[15];
    const float* ln2_b      = (const float*)d_in[16];
    const float* W1         = (const float*)d_in[17];
    const float* b1         = (const float*)d_in[18];
    const float* W2         = (const float*)d_in[19];
    const float* b2         = (const float*)d_in[20];

    const int M = BB * LL;            // 4096
    char* ws = (char*)d_ws;
    size_t off = 0;
    // y_ln..Vt (25.17MB) is reused as the FF2 bf16 split-K4 partial buffer.
    bf16* y_ln  = (bf16*)(ws + off); off += (size_t)M * DD * 2;
    bf16* Qh    = (bf16*)(ws + off); off += (size_t)M * DD * 2;
    bf16* Kh    = (bf16*)(ws + off); off += (size_t)M * DD * 2;
    bf16* Vt    = (bf16*)(ws + off); off += (size_t)M * DD * 2;
    bf16* attn  = (bf16*)(ws + off); off += (size_t)M * DD * 2;
    bf16* h2    = (bf16*)(ws + off); off += (size_t)M * DD * 2;
    float* out1 = (float*)(ws + off); off += (size_t)M * DD * 4;
    bf16* ff1   = (bf16*)(ws + off); off += (size_t)M * FF_ * 2;
    bf16* WtQKV = (bf16*)(ws + off); off += (size_t)2304 * DD * 2;
    bf16* WtO   = (bf16*)(ws + off); off += (size_t)DD * DD * 2;
    bf16* Wt1   = (bf16*)(ws + off); off += (size_t)FF_ * DD * 2;
    bf16* Wt2   = (bf16*)(ws + off); off += (size_t)DD * FF_ * 2;
    float* bqkv = (float*)(ws + off); off += (size_t)2304 * 4;
    bf16*  PartF2 = (bf16*)ws;    // [4][M][DD] bf16 == y_ln..Vt region

    // 0+1. LN1 + weight transposes + bias pack
    prep_ln<<<11017, 256, 0, stream>>>(x, ln1_g, ln1_b, Wq, Wk, Wv, Wo, W1, W2,
                                       bq, bk, bv, y_ln, WtQKV, WtO, Wt1, Wt2, bqkv);

    // 2. fused QKV projection, 64x128 tiles (1152 blocks, 4.5/CU)
    mfma_gemm_bt<64, 128, 0, false, true, 1, bf16><<<dim3(2304 / 128, M / 64), 256, 0, stream>>>(
        y_ln, WtQKV, bqkv, nullptr, (bf16*)nullptr, Qh, Kh, Vt, M, 2304, DD);

    // 3. flash attention
    flash_attn_kernel<<<dim3(LL / 64, HH, BB), 256, 0, stream>>>(
        Qh, Kh, Vt, postag_ids, lex_mask, rel_emb, pt_table, attn);

    // 4. Wo projection, 64x64 tiles (768 blocks, 3/CU), unsplit, fused +bo +x -> out1 fp32
    mfma_gemm_bt<64, 64, 2, false, false, 1, float><<<dim3(DD / 64, M / 64), 256, 0, stream>>>(
        attn, WtO, bo, x, out1, nullptr, nullptr, nullptr, M, DD, DD);

    // 5. LN2 (plain apply on out1)
    ln_kernel<<<M, 256, 0, stream>>>(out1, ln2_g, ln2_b, 1e-5f, h2);

    // 6. FF1 + exact GELU, 128x128 tiles (traffic/occupancy equilibrium; see GEMM note)
    mfma_gemm_bt<128, 128, 0, true, false, 1, bf16><<<dim3(FF_ / 128, M / 128), 256, 0, stream>>>(
        h2, Wt1, b1, nullptr, ff1, nullptr, nullptr, nullptr, M, FF_, DD);

    // 7. FF2 split-K=4, bf16 partials, 128x128 tiles
    mfma_gemm_bt<128, 128, 0, false, false, 4, bf16><<<dim3(DD / 128, M / 128, 4), 256, 0, stream>>>(
        ff1, Wt2, nullptr, nullptr, PartF2, nullptr, nullptr, nullptr, M, DD, FF_);

    // 8. FF2 reduce + b2 + out1 residual -> d_out
    ff2_reduce<<<(M * DD / 8) / 256, 256, 0, stream>>>(PartF2, out1, b2, (float*)d_out);
}

// Round 16
// 288.582 us; speedup vs baseline: 1.0756x; 1.0041x over previous
//
#include <hip/hip_runtime.h>
#include <hip/hip_bf16.h>
#include <math.h>

typedef __hip_bfloat16 bf16;
typedef __attribute__((ext_vector_type(8))) short short8;
typedef __attribute__((ext_vector_type(4))) float f32x4;

#define BB 4
#define LL 1024
#define DD 768
#define HH 12
#define DK 64
#define FF_ 3072
#define PP 32
#define MAXD 256

// async global->LDS, 16B per lane. LDS dest: wave-uniform base + lane*16.
__device__ __forceinline__ void async_load16(const void* g, void* l) {
    __builtin_amdgcn_global_load_lds(
        (const __attribute__((address_space(1))) unsigned int*)g,
        (__attribute__((address_space(3))) unsigned int*)l, 16, 0, 0);
}

// ---------------- LayerNorm (fp32 in, bf16 out) ----------------
__global__ __launch_bounds__(256) void ln_kernel(const float* __restrict__ x,
                                                 const float* __restrict__ g,
                                                 const float* __restrict__ b,
                                                 float eps,
                                                 bf16* __restrict__ y) {
    const int row = blockIdx.x;
    const int tid = threadIdx.x;
    const float* xr = x + (size_t)row * DD;

    float v[3];
    float s = 0.f, ss = 0.f;
#pragma unroll
    for (int i = 0; i < 3; ++i) {
        float t = xr[tid + i * 256];
        v[i] = t; s += t; ss += t * t;
    }
    __shared__ float rs[256], rss[256];
    rs[tid] = s; rss[tid] = ss;
    __syncthreads();
    for (int off = 128; off; off >>= 1) {
        if (tid < off) { rs[tid] += rs[tid + off]; rss[tid] += rss[tid + off]; }
        __syncthreads();
    }
    const float mean = rs[0] * (1.f / DD);
    const float var  = rss[0] * (1.f / DD) - mean * mean;
    const float inv  = rsqrtf(var + eps);
#pragma unroll
    for (int i = 0; i < 3; ++i) {
        int c = tid + i * 256;
        y[(size_t)row * DD + c] = __float2bfloat16((v[i] - mean) * inv * g[c] + b[c]);
    }
}

// ---------------- fused: LN1 + all weight transposes + bias pack ----------------
__global__ __launch_bounds__(256) void prep_ln(
        const float* __restrict__ x,
        const float* __restrict__ ln1_g, const float* __restrict__ ln1_b,
        const float* __restrict__ Wq, const float* __restrict__ Wk,
        const float* __restrict__ Wv, const float* __restrict__ Wo,
        const float* __restrict__ W1, const float* __restrict__ W2,
        const float* __restrict__ bq, const float* __restrict__ bk,
        const float* __restrict__ bv,
        bf16* __restrict__ y_ln,
        bf16* __restrict__ WtQKV, bf16* __restrict__ WtO,
        bf16* __restrict__ Wt1, bf16* __restrict__ Wt2,
        float* __restrict__ bqkv) {
    const int bid = blockIdx.x;
    const int tid = threadIdx.x;

    if (bid < 4096) {                       // ---- LN1 ----
        const float* xr = x + (size_t)bid * DD;
        float v[3];
        float s = 0.f, ss = 0.f;
#pragma unroll
        for (int i = 0; i < 3; ++i) {
            float t = xr[tid + i * 256];
            v[i] = t; s += t; ss += t * t;
        }
        __shared__ float rs[256], rss[256];
        rs[tid] = s; rss[tid] = ss;
        __syncthreads();
        for (int off = 128; off; off >>= 1) {
            if (tid < off) { rs[tid] += rs[tid + off]; rss[tid] += rss[tid + off]; }
            __syncthreads();
        }
        const float mean = rs[0] * (1.f / DD);
        const float var  = rss[0] * (1.f / DD) - mean * mean;
        const float inv  = rsqrtf(var + 1e-6f);
#pragma unroll
        for (int i = 0; i < 3; ++i) {
            int c = tid + i * 256;
            y_ln[(size_t)bid * DD + c] = __float2bfloat16((v[i] - mean) * inv * ln1_g[c] + ln1_b[c]);
        }
        return;
    }
    if (bid >= 11008) {                     // ---- bias pack ----
        int i = (bid - 11008) * 256 + tid;
        if (i < 2304) {
            float v = (i < 768) ? bq[i] : (i < 1536) ? bk[i - 768] : bv[i - 1536];
            bqkv[i] = v;
        }
        return;
    }
    // ---- transposes ----
    const int tb = bid - 4096;
    const float* W; bf16* Wt; int K, N, tile;
    if (tb < 576)       { W = Wq; Wt = WtQKV;                      K = DD;  N = DD;  tile = tb; }
    else if (tb < 1152) { W = Wk; Wt = WtQKV + (size_t)768 * DD;   K = DD;  N = DD;  tile = tb - 576; }
    else if (tb < 1728) { W = Wv; Wt = WtQKV + (size_t)1536 * DD;  K = DD;  N = DD;  tile = tb - 1152; }
    else if (tb < 2304) { W = Wo; Wt = WtO;                        K = DD;  N = DD;  tile = tb - 1728; }
    else if (tb < 4608) { W = W1; Wt = Wt1;                        K = DD;  N = FF_; tile = tb - 2304; }
    else                { W = W2; Wt = Wt2;                        K = FF_; N = DD;  tile = tb - 4608; }
    const int ntn = N / 32;
    const int n0 = (tile % ntn) * 32, k0 = (tile / ntn) * 32;

    __shared__ float tilebuf[32][33];
    const int tx = tid & 31, ty = tid >> 5;
#pragma unroll
    for (int i = 0; i < 4; ++i) {
        int k = ty + i * 8;
        tilebuf[k][tx] = W[(size_t)(k0 + k) * N + n0 + tx];
    }
    __syncthreads();
#pragma unroll
    for (int i = 0; i < 4; ++i) {
        int n = ty + i * 8;
        Wt[(size_t)(n0 + n) * K + k0 + tx] = __float2bfloat16(tilebuf[tx][n]);
    }
}

// ---------------- FF2 split-K(4, bf16 partials) reduce + bias + out1 residual ----------------
__global__ __launch_bounds__(256) void ff2_reduce(const bf16* __restrict__ Fp,
                                                  const float* __restrict__ out1,
                                                  const float* __restrict__ b2,
                                                  float* __restrict__ dout) {
    const size_t stride = (size_t)BB * LL * DD;
    const size_t i8 = ((size_t)blockIdx.x * 256 + threadIdx.x) * 8;
    const int c = (int)(i8 % DD);

    float acc[8];
    float4 r0 = *(const float4*)(out1 + i8);
    float4 r1 = *(const float4*)(out1 + i8 + 4);
    float4 bb0 = *(const float4*)(b2 + c);
    float4 bb1 = *(const float4*)(b2 + c + 4);
    acc[0] = r0.x + bb0.x; acc[1] = r0.y + bb0.y; acc[2] = r0.z + bb0.z; acc[3] = r0.w + bb0.w;
    acc[4] = r1.x + bb1.x; acc[5] = r1.y + bb1.y; acc[6] = r1.z + bb1.z; acc[7] = r1.w + bb1.w;
#pragma unroll
    for (int p = 0; p < 4; ++p) {
        short8 v = *(const short8*)(Fp + p * stride + i8);
#pragma unroll
        for (int k = 0; k < 8; ++k) acc[k] += __bfloat162float(((const bf16*)&v)[k]);
    }
    float4 o0 = {acc[0], acc[1], acc[2], acc[3]};
    float4 o1 = {acc[4], acc[5], acc[6], acc[7]};
    *(float4*)(dout + i8) = o0;
    *(float4*)(dout + i8 + 4) = o1;
}

// ---------------- MFMA GEMM: templated TMxTN tile, WRMxWRN wave grid, dbuf LDS, XCD swizzle ----------------
// C = act(A @ Bt^T + bias) (+res). BK=32. Block = WRM*WRN waves; wave sub-tile (TM/WRM)x(TN/WRN).
// Grid must satisfy gridDim.y*gridDim.z % 8 == 0 for the XCD swizzle.
// Tile-size notes (measured): FF at 64x128 raises occupancy but +50% HBM traffic -> total
// regresses (r14). This round: 128x128 with 8 waves (512 thr) = same traffic, 2.4x waves/CU.
template <int TM, int TN, int WRM, int WRN, int RES, bool GELU, bool SPLIT_QKV, int KSPLIT, typename OutT>
__global__ __launch_bounds__(WRM * WRN * 64) void mfma_gemm_bt(const bf16* __restrict__ A,
                                                    const bf16* __restrict__ Bt,
                                                    const float* __restrict__ bias,
                                                    const float* __restrict__ res,
                                                    OutT* __restrict__ C,
                                                    bf16* __restrict__ QhOut,
                                                    bf16* __restrict__ KhOut,
                                                    bf16* __restrict__ VtOut,
                                                    int M, int N, int K) {
    constexpr int NW = WRM * WRN;            // waves per block
    constexpr int WM = TM / WRM / 16;        // m-frags per wave
    constexpr int WN = TN / WRN / 16;        // n-frags per wave
    constexpr int CA = TM / 16 / NW;         // A staging instrs per wave
    constexpr int CB = TN / 16 / NW;
    static_assert(CA >= 1 && CB >= 1, "wave count too large for tile");
    __shared__ short As[2][TM * 32];
    __shared__ short Bs[2][TN * 32];

    const int L = blockIdx.x + gridDim.x * (blockIdx.y + gridDim.y * blockIdx.z);
    const int xcd = L & 7, j = L >> 3;
    const int col = j % gridDim.x;
    const int panel = xcd + 8 * (j / gridDim.x);
    const int byy = panel % gridDim.y;
    const int bzz = panel / gridDim.y;

    const int bm = byy * TM, bn = col * TN;
    const int tid = threadIdx.x;
    const int w = tid >> 6, lane = tid & 63;
    const int c16 = lane & 15, quad = lane >> 4;
    const int wy = w / WRN, wx = w % WRN;

    const int srow_in = lane >> 2;
    const int cg = (lane & 3) ^ quad;

    const int Ksub = K / KSPLIT;
    const int kbase = bzz * Ksub;

    f32x4 acc[WM][WN];
#pragma unroll
    for (int i = 0; i < WM; ++i)
#pragma unroll
        for (int j2 = 0; j2 < WN; ++j2) acc[i][j2] = (f32x4)0.f;

    auto stage = [&](int buf, int k0) {
#pragma unroll
        for (int j2 = 0; j2 < CA; ++j2) {
            const int ci = w * CA + j2;
            const int row = ci * 16 + srow_in;
            async_load16(A + (size_t)(bm + row) * K + k0 + cg * 8, (char*)As[buf] + ci * 1024);
        }
#pragma unroll
        for (int j2 = 0; j2 < CB; ++j2) {
            const int ci = w * CB + j2;
            const int row = ci * 16 + srow_in;
            async_load16(Bt + (size_t)(bn + row) * K + k0 + cg * 8, (char*)Bs[buf] + ci * 1024);
        }
    };

    const int nIter = Ksub / 32;
    stage(0, kbase);
    for (int kt = 0; kt < nIter; ++kt) {
        const int buf = kt & 1;
        __syncthreads();
        if (kt + 1 < nIter) stage(buf ^ 1, kbase + (kt + 1) * 32);

        short8 af[WM], bf[WN];
#pragma unroll
        for (int i = 0; i < WM; ++i) {
            const int ra = wy * (WM * 16) + i * 16 + c16;
            const int ca = quad ^ ((ra >> 2) & 3);
            af[i] = *(const short8*)((const char*)As[buf] + ra * 64 + ca * 16);
        }
#pragma unroll
        for (int i = 0; i < WN; ++i) {
            const int rb = wx * (WN * 16) + i * 16 + c16;
            const int cb = quad ^ ((rb >> 2) & 3);
            bf[i] = *(const short8*)((const char*)Bs[buf] + rb * 64 + cb * 16);
        }
#pragma unroll
        for (int mi = 0; mi < WM; ++mi)
#pragma unroll
            for (int ni = 0; ni < WN; ++ni)
                acc[mi][ni] = __builtin_amdgcn_mfma_f32_16x16x32_bf16(af[mi], bf[ni], acc[mi][ni], 0, 0, 0);
    }

    if (KSPLIT > 1) {
        OutT* Cp = C + (size_t)bzz * M * N;
#pragma unroll
        for (int mi = 0; mi < WM; ++mi)
#pragma unroll
            for (int ni = 0; ni < WN; ++ni) {
                const int n = bn + wx * (WN * 16) + ni * 16 + c16;
#pragma unroll
                for (int r = 0; r < 4; ++r) {
                    const int m = bm + wy * (WM * 16) + mi * 16 + quad * 4 + r;
                    if constexpr (sizeof(OutT) == 2)
                        Cp[(size_t)m * N + n] = __float2bfloat16(acc[mi][ni][r]);
                    else
                        Cp[(size_t)m * N + n] = acc[mi][ni][r];
                }
            }
        return;
    }

    if (SPLIT_QKV) {
        bf16* dst; int base;
        if (bn < 768)       { dst = QhOut; base = 0; }
        else if (bn < 1536) { dst = KhOut; base = 768; }
        else                { dst = VtOut; base = 1536; }
#pragma unroll
        for (int mi = 0; mi < WM; ++mi) {
#pragma unroll
            for (int ni = 0; ni < WN; ++ni) {
                const int nfull = bn + wx * (WN * 16) + ni * 16 + c16;
                const float bv = bias[nfull];
                const int nr = nfull - base;
                const int hv = nr >> 6, dv = nr & 63;
#pragma unroll
                for (int r = 0; r < 4; ++r) {
                    const int m = bm + wy * (WM * 16) + mi * 16 + quad * 4 + r;
                    const float v = acc[mi][ni][r] + bv;
                    const size_t bh = (size_t)((m >> 10) * HH + hv);
                    if (base == 1536)   // V: [b][h][d][s]
                        dst[(bh * DK + dv) * LL + (m & 1023)] = __float2bfloat16(v);
                    else                // Q/K: [b][h][s][d]
                        dst[(bh * LL + (m & 1023)) * DK + dv] = __float2bfloat16(v);
                }
            }
        }
        return;
    }

#pragma unroll
    for (int mi = 0; mi < WM; ++mi) {
#pragma unroll
        for (int ni = 0; ni < WN; ++ni) {
            const int n = bn + wx * (WN * 16) + ni * 16 + c16;
            const float bv = bias[n];
#pragma unroll
            for (int r = 0; r < 4; ++r) {
                const int m = bm + wy * (WM * 16) + mi * 16 + quad * 4 + r;
                float v = acc[mi][ni][r] + bv;
                if (GELU) v = 0.5f * v * (1.f + erff(v * 0.70710678118f));
                if (RES == 2) v += res[(size_t)m * N + n];
                if constexpr (sizeof(OutT) == 2)
                    C[(size_t)m * N + n] = __float2bfloat16(v);
                else
                    C[(size_t)m * N + n] = v;
            }
        }
    }
}

// ---------------- Flash attention: pipelined staging (K double-buffered, V phase-split) ----------------
// Session-verified best. Elimination record (r3..r11): DMA-latency cover, barrier halving,
// in-wave ILP reorder all NEUTRAL; per-wave global K/V loads (-58us), conflicting vector
// P-transpose (-22us), VMEM table gathers (-49us) all WORSE. Measured local optimum.
__global__ __launch_bounds__(256) void flash_attn_kernel(
        const bf16* __restrict__ Qh, const bf16* __restrict__ Kh, const bf16* __restrict__ Vt,
        const int* __restrict__ postag, const float* __restrict__ lex,
        const float* __restrict__ rel_emb, const float* __restrict__ pt_table,
        bf16* __restrict__ O) {
    const int qt = blockIdx.x;
    const int h  = blockIdx.y;
    const int b  = blockIdx.z;
    const int tid  = threadIdx.x;
    const int w    = tid >> 6;
    const int lane = tid & 63;
    const int c    = lane & 15;
    const int quad = lane >> 4;

    __shared__ short Ks[2][4096];       // double-buffered K tile (2 x 8KB)
    __shared__ short Vs[4096];          // single V tile (8KB)
    __shared__ bf16  Ps[4][16][72];
    __shared__ f32x4 relT[516];
    __shared__ float pt_col[1024];
    __shared__ float lex_f[LL];
    __shared__ short ps_f[LL];
    // LDS total: 16384+8192+9216+8256+4096+4096+2048 = 52288 B -> 3 blocks/CU (limit 53333)

    for (int i = tid; i < 516; i += 256) {
        f32x4 t;
        t[0] = rel_emb[min(i, 512) * HH + h];
        t[1] = rel_emb[min(max(i - 1, 0), 512) * HH + h];
        t[2] = rel_emb[min(max(i - 2, 0), 512) * HH + h];
        t[3] = rel_emb[min(max(i - 3, 0), 512) * HH + h];
        relT[i] = t;
    }
    for (int i = tid; i < 1024; i += 256) {
        pt_col[i] = pt_table[i * HH + h];
        lex_f[i]  = lex[b * LL + i];
        ps_f[i]   = (short)postag[b * LL + i];
    }

    const int q0 = qt * 64 + w * 16;
    const size_t bh = (size_t)(b * HH + h);
    const bf16* Kbase = Kh + bh * LL * DK;
    const bf16* Vbase = Vt + bh * DK * LL;

    const int srow = lane >> 3;
    const int schunk = lane & 7;

    // prologue: stage K(0) -> Ks[0]
#pragma unroll
    for (int j = 0; j < 2; ++j) {
        const int row = w * 16 + j * 8 + srow;
        const int g = schunk ^ (row & 7);
        async_load16(Kbase + (size_t)row * DK + g * 8,
                     (char*)Ks[0] + (w * 16 + j * 8) * 128);
    }

    short8 qf0, qf1;
    {
        const bf16* qp = Qh + (bh * LL + q0 + c) * DK + quad * 8;
        qf0 = *(const short8*)qp;
        qf1 = *(const short8*)(qp + 32);
    }
    int plx_r[4];
#pragma unroll
    for (int r = 0; r < 4; ++r) plx_r[r] = postag[b * LL + q0 + quad * 4 + r] * PP;

    f32x4 o_acc[4];
#pragma unroll
    for (int t = 0; t < 4; ++t) o_acc[t] = (f32x4)0.f;
    float lsum[4] = {0.f, 0.f, 0.f, 0.f};

    __syncthreads();   // drains K(0); LDS tables visible

    for (int tt = 0; tt < LL / 64; ++tt) {
        const int s0 = tt * 64;
        const int cur = tt & 1;
        const short* Kc = Ks[cur];

        // issue V(tt) -> Vs (write-safe: all waves past previous endsync)
#pragma unroll
        for (int j = 0; j < 2; ++j) {
            const int row = w * 16 + j * 8 + srow;
            const int g = schunk ^ (row & 7);
            async_load16(Vbase + (size_t)row * LL + s0 + g * 8,
                         (char*)Vs + (w * 16 + j * 8) * 128);
        }

        // ---- Phase 1: QK^T on Ks[cur] + softmax + Ps (no Vs dependency) ----
        f32x4 S[4];
#pragma unroll
        for (int t = 0; t < 4; ++t) {
            const int r = t * 16 + c;
            short8 kf0 = *(const short8*)&Kc[r * 64 + ((quad ^ (r & 7)) * 8)];
            short8 kf1 = *(const short8*)&Kc[r * 64 + (((4 + quad) ^ (r & 7)) * 8)];
            f32x4 a = (f32x4)0.f;
            a = __builtin_amdgcn_mfma_f32_16x16x32_bf16(qf0, kf0, a, 0, 0, 0);
            a = __builtin_amdgcn_mfma_f32_16x16x32_bf16(qf1, kf1, a, 0, 0, 0);
            S[t] = a;
        }

        const int d0 = s0 - q0;
        if (d0 >= 271 || d0 <= -319) {
            const float rcv = (d0 >= 271) ? relT[515][0] : relT[0][0];
#pragma unroll
            for (int t = 0; t < 4; ++t) {
                const int s_glob = s0 + t * 16 + c;
                const float lx = lex_f[s_glob] + rcv;
                const int   ps = ps_f[s_glob];
#pragma unroll
                for (int r = 0; r < 4; ++r) {
                    float e = __expf(S[t][r] * 0.125f + pt_col[plx_r[r] + ps] + lx);
                    S[t][r] = e;
                    lsum[r] += e;
                }
            }
        } else {
            const int ebase = d0 - quad * 4 + 256;
#pragma unroll
            for (int t = 0; t < 4; ++t) {
                const int s_loc = t * 16 + c;
                const int s_glob = s0 + s_loc;
                const float lx = lex_f[s_glob];
                const int   ps = ps_f[s_glob];
                const int e = min(max(ebase + s_loc, 0), 515);
                f32x4 rv = relT[e];
#pragma unroll
                for (int r = 0; r < 4; ++r) {
                    float ev = __expf(S[t][r] * 0.125f + rv[r] + pt_col[plx_r[r] + ps] + lx);
                    S[t][r] = ev;
                    lsum[r] += ev;
                }
            }
        }

#pragma unroll
        for (int t = 0; t < 4; ++t)
#pragma unroll
            for (int r = 0; r < 4; ++r)
                Ps[w][quad * 4 + r][t * 16 + c] = __float2bfloat16(S[t][r]);

        short8 pa0 = *(const short8*)&Ps[w][c][quad * 8];
        short8 pa1 = *(const short8*)&Ps[w][c][quad * 8 + 32];

        __syncthreads();   // midsync: drains V(tt) (covered by Phase 1)

        // issue K(tt+1) -> Ks[cur^1] (write-safe: its readers finished before prev midsync)
        if (tt + 1 < LL / 64) {
#pragma unroll
            for (int j = 0; j < 2; ++j) {
                const int row = w * 16 + j * 8 + srow;
                const int g = schunk ^ (row & 7);
                async_load16(Kbase + (size_t)(s0 + 64 + row) * DK + g * 8,
                             (char*)Ks[cur ^ 1] + (w * 16 + j * 8) * 128);
            }
        }

        // ---- Phase 2: PV on Vs ----
#pragma unroll
        for (int t = 0; t < 4; ++t) {
            const int r = t * 16 + c;
            short8 vf0 = *(const short8*)&Vs[r * 64 + ((quad ^ (r & 7)) * 8)];
            short8 vf1 = *(const short8*)&Vs[r * 64 + (((4 + quad) ^ (r & 7)) * 8)];
            o_acc[t] = __builtin_amdgcn_mfma_f32_16x16x32_bf16(pa0, vf0, o_acc[t], 0, 0, 0);
            o_acc[t] = __builtin_amdgcn_mfma_f32_16x16x32_bf16(pa1, vf1, o_acc[t], 0, 0, 0);
        }

        __syncthreads();   // endsync: drains K(tt+1) (covered by Phase 2); protects Vs overwrite
    }

#pragma unroll
    for (int mm = 1; mm < 16; mm <<= 1)
#pragma unroll
        for (int r = 0; r < 4; ++r) lsum[r] += __shfl_xor(lsum[r], mm);

    float inv_l[4];
#pragma unroll
    for (int r = 0; r < 4; ++r) inv_l[r] = 1.f / lsum[r];
#pragma unroll
    for (int t = 0; t < 4; ++t)
#pragma unroll
        for (int r = 0; r < 4; ++r) {
            const int row = q0 + quad * 4 + r;
            O[((size_t)(b * LL + row)) * DD + h * DK + t * 16 + c] =
                __float2bfloat16(o_acc[t][r] * inv_l[r]);
        }
}

extern "C" void kernel_launch(void* const* d_in, const int* in_sizes, int n_in,
                              void* d_out, int out_size, void* d_ws, size_t ws_size,
                              hipStream_t stream) {
    const float* x          = (const float*)d_in[0];
    const int*   postag_ids = (const int*)d_in[1];
    const float* lex_mask   = (const float*)d_in[2];
    const float* ln1_g      = (const float*)d_in[3];
    const float* ln1_b      = (const float*)d_in[4];
    const float* Wq         = (const float*)d_in[5];
    const float* bq         = (const float*)d_in[6];
    const float* Wk         = (const float*)d_in[7];
    const float* bk         = (const float*)d_in[8];
    const float* Wv         = (const float*)d_in[9];
    const float* bv         = (const float*)d_in[10];
    const float* Wo         = (const float*)d_in[11];
    const float* bo         = (const float*)d_in[12];
    const float* rel_emb    = (const float*)d_in[13];
    const float* pt_table   = (const float*)d_in[14];
    const float* ln2_g      = (const float*)d_in[15];
    const float* ln2_b      = (const float*)d_in[16];
    const float* W1         = (const float*)d_in[17];
    const float* b1         = (const float*)d_in[18];
    const float* W2         = (const float*)d_in[19];
    const float* b2         = (const float*)d_in[20];

    const int M = BB * LL;            // 4096
    char* ws = (char*)d_ws;
    size_t off = 0;
    // y_ln..Vt (25.17MB) is reused as the FF2 bf16 split-K4 partial buffer.
    bf16* y_ln  = (bf16*)(ws + off); off += (size_t)M * DD * 2;
    bf16* Qh    = (bf16*)(ws + off); off += (size_t)M * DD * 2;
    bf16* Kh    = (bf16*)(ws + off); off += (size_t)M * DD * 2;
    bf16* Vt    = (bf16*)(ws + off); off += (size_t)M * DD * 2;
    bf16* attn  = (bf16*)(ws + off); off += (size_t)M * DD * 2;
    bf16* h2    = (bf16*)(ws + off); off += (size_t)M * DD * 2;
    float* out1 = (float*)(ws + off); off += (size_t)M * DD * 4;
    bf16* ff1   = (bf16*)(ws + off); off += (size_t)M * FF_ * 2;
    bf16* WtQKV = (bf16*)(ws + off); off += (size_t)2304 * DD * 2;
    bf16* WtO   = (bf16*)(ws + off); off += (size_t)DD * DD * 2;
    bf16* Wt1   = (bf16*)(ws + off); off += (size_t)FF_ * DD * 2;
    bf16* Wt2   = (bf16*)(ws + off); off += (size_t)DD * FF_ * 2;
    float* bqkv = (float*)(ws + off); off += (size_t)2304 * 4;
    bf16*  PartF2 = (bf16*)ws;    // [4][M][DD] bf16 == y_ln..Vt region

    // 0+1. LN1 + weight transposes + bias pack
    prep_ln<<<11017, 256, 0, stream>>>(x, ln1_g, ln1_b, Wq, Wk, Wv, Wo, W1, W2,
                                       bq, bk, bv, y_ln, WtQKV, WtO, Wt1, Wt2, bqkv);

    // 2. fused QKV projection, 64x128 tiles, 4 waves (unchanged verified config)
    mfma_gemm_bt<64, 128, 2, 2, 0, false, true, 1, bf16><<<dim3(2304 / 128, M / 64), 256, 0, stream>>>(
        y_ln, WtQKV, bqkv, nullptr, (bf16*)nullptr, Qh, Kh, Vt, M, 2304, DD);

    // 3. flash attention
    flash_attn_kernel<<<dim3(LL / 64, HH, BB), 256, 0, stream>>>(
        Qh, Kh, Vt, postag_ids, lex_mask, rel_emb, pt_table, attn);

    // 4. Wo projection, 64x64 tiles, 4 waves, fused +bo +x -> out1 fp32 (unchanged)
    mfma_gemm_bt<64, 64, 2, 2, 2, false, false, 1, float><<<dim3(DD / 64, M / 64), 256, 0, stream>>>(
        attn, WtO, bo, x, out1, nullptr, nullptr, nullptr, M, DD, DD);

    // 5. LN2 (plain apply on out1)
    ln_kernel<<<M, 256, 0, stream>>>(out1, ln2_g, ln2_b, 1e-5f, h2);

    // 6. FF1 + exact GELU, 128x128 tiles, 8 waves (512 thr): same traffic, 24 waves/CU vs 12
    mfma_gemm_bt<128, 128, 4, 2, 0, true, false, 1, bf16><<<dim3(FF_ / 128, M / 128), 512, 0, stream>>>(
        h2, Wt1, b1, nullptr, ff1, nullptr, nullptr, nullptr, M, FF_, DD);

    // 7. FF2 split-K=4, bf16 partials, 128x128 tiles, 8 waves (512 thr)
    mfma_gemm_bt<128, 128, 4, 2, 0, false, false, 4, bf16><<<dim3(DD / 128, M / 128, 4), 512, 0, stream>>>(
        ff1, Wt2, nullptr, nullptr, PartF2, nullptr, nullptr, nullptr, M, DD, FF_);

    // 8. FF2 reduce + b2 + out1 residual -> d_out
    ff2_reduce<<<(M * DD / 8) / 256, 256, 0, stream>>>(PartF2, out1, b2, (float*)d_out);
}